// Round 2
// baseline (506.571 us; speedup 1.0000x reference)
//
#include <hip/hip_runtime.h>

// FilteredPatchLoss: B=64, H=W=1024, p=16.
// Stripe = (b, ih): 16 rows x 1024 cols = 16384 floats, 64 patches per stripe.
// Thread t owns float4-column t (patch t/4) within each stripe.
//
// R4: main-kernel BW push. R3 proved the 2x1GiB ws-poison fills (~324 us) are
// unconditional harness cost; the controllable remainder is the main kernel
// at ~160 us = 3.4 TB/s (54% of 6.3 TB/s achievable). Old structure staged
// 32 float4 in registers (128 payload VGPRs -> ~150 total -> 2 waves/SIMD)
// and burst-stalled on vmcnt with a 400-cyc serial tail. Now: chunked
// accumulate (4 rows/chunk, o/g interleaved, ~45 live VGPRs) +
// __launch_bounds__(256,4) (cap 128 VGPR -> 4 waves/SIMD, room to prefetch
// next chunk) + 2 contiguous stripes per block (2048 blocks; stripe-1 loads
// overlap stripe-0 reduce tail). Accumulation order identical to R3.

#define PATCH 16
#define WIDTH 1024
#define SPB 2  // stripes per block

// 4096 stripes * 4 waves = 16384 per-(stripe,wave) partials (128 KB .bss)
#define MAX_PARTIALS 16384

__device__ float2 g_partials[MAX_PARTIALS];

__global__ __launch_bounds__(256, 4) void patch_loss_kernel(
    const float* __restrict__ outp, const float* __restrict__ tgtp,
    const int* __restrict__ filter_rate_p)
{
    const int t = threadIdx.x;
    const float fr = (float)(*filter_rate_p);

#pragma unroll
    for (int s = 0; s < SPB; ++s) {
        const int stripe = blockIdx.x * SPB + s;
        const long long base = (long long)stripe * (PATCH * WIDTH);
        const float4* op = (const float4*)(outp + base) + t;
        const float4* tp = (const float4*)(tgtp + base) + t;

        float ts = 0.f, ls = 0.f;
#pragma unroll
        for (int kc = 0; kc < 16; kc += 4) {
            // o/g interleaved: first accumulate waits on 2 loads, not 17.
            float4 o0 = op[(kc + 0) * 256];
            float4 g0 = tp[(kc + 0) * 256];
            float4 o1 = op[(kc + 1) * 256];
            float4 g1 = tp[(kc + 1) * 256];
            float4 o2 = op[(kc + 2) * 256];
            float4 g2 = tp[(kc + 2) * 256];
            float4 o3 = op[(kc + 3) * 256];
            float4 g3 = tp[(kc + 3) * 256];

            ts += (g0.x + g0.y) + (g0.z + g0.w);
            ls += (fabsf(o0.x - g0.x) + fabsf(o0.y - g0.y)) +
                  (fabsf(o0.z - g0.z) + fabsf(o0.w - g0.w));
            ts += (g1.x + g1.y) + (g1.z + g1.w);
            ls += (fabsf(o1.x - g1.x) + fabsf(o1.y - g1.y)) +
                  (fabsf(o1.z - g1.z) + fabsf(o1.w - g1.w));
            ts += (g2.x + g2.y) + (g2.z + g2.w);
            ls += (fabsf(o2.x - g2.x) + fabsf(o2.y - g2.y)) +
                  (fabsf(o2.z - g2.z) + fabsf(o2.w - g2.w));
            ts += (g3.x + g3.y) + (g3.z + g3.w);
            ls += (fabsf(o3.x - g3.x) + fabsf(o3.y - g3.y)) +
                  (fabsf(o3.z - g3.z) + fabsf(o3.w - g3.w));
        }

        // Patch p <- lanes 4p..4p+3 (contiguous, same wave).
        ts += __shfl_xor(ts, 1, 64);
        ls += __shfl_xor(ls, 1, 64);
        ts += __shfl_xor(ts, 2, 64);
        ls += __shfl_xor(ls, 2, 64);

        const bool live = ((t & 3) == 0) && (ts * (1.0f / 256.0f) > fr);
        float loss = live ? ls * (1.0f / 256.0f) : 0.0f;
        float cnt  = live ? 1.0f : 0.0f;

#pragma unroll
        for (int off = 4; off <= 32; off <<= 1) {
            loss += __shfl_xor(loss, off, 64);
            cnt  += __shfl_xor(cnt,  off, 64);
        }
        if ((t & 63) == 0)
            g_partials[(stripe << 2) | (t >> 6)] = make_float2(loss, cnt);
    }
}

// Single block: reduce 16384 (loss, cnt) pairs and finalize.
__global__ __launch_bounds__(1024) void reduce_kernel(
    float* __restrict__ out, int nf4)  // nf4 = nwaves/2 float4 views
{
    const int t = threadIdx.x;
    const float4* p = (const float4*)g_partials;
    float l = 0.f, c = 0.f;
    for (int i = t; i < nf4; i += 1024) {
        float4 v = p[i];
        l += v.x + v.z;
        c += v.y + v.w;
    }
#pragma unroll
    for (int off = 1; off <= 32; off <<= 1) {
        l += __shfl_xor(l, off, 64);
        c += __shfl_xor(c, off, 64);
    }
    __shared__ float sl[16], sc[16];
    if ((t & 63) == 0) { sl[t >> 6] = l; sc[t >> 6] = c; }
    __syncthreads();
    if (t < 64) {  // one full wave active -> shuffles well-defined
        l = (t < 16) ? sl[t] : 0.f;
        c = (t < 16) ? sc[t] : 0.f;
#pragma unroll
        for (int off = 1; off <= 8; off <<= 1) {
            l += __shfl_xor(l, off, 64);
            c += __shfl_xor(c, off, 64);
        }
        if (t == 0) out[0] = l / c;
    }
}

extern "C" void kernel_launch(void* const* d_in, const int* in_sizes, int n_in,
                              void* d_out, int out_size, void* d_ws, size_t ws_size,
                              hipStream_t stream)
{
    const float* outp = (const float*)d_in[0];
    const float* tgtp = (const float*)d_in[1];
    // d_in[2] = patch_size (16, structure hard-coded), d_in[3] = filter_rate
    const int* filter_rate_p = (const int*)d_in[3];

    const long long total = (long long)in_sizes[0];          // B*H*W
    const int nstripes = (int)(total / (PATCH * WIDTH));     // 4096
    const int nblocks = nstripes / SPB;                      // 2048
    const int nf4 = nstripes * 2;                            // nwaves/2 = 8192

    patch_loss_kernel<<<nblocks, 256, 0, stream>>>(outp, tgtp, filter_rate_p);
    reduce_kernel<<<1, 1024, 0, stream>>>((float*)d_out, nf4);
}